// Round 1
// baseline (1464.573 us; speedup 1.0000x reference)
//
#include <hip/hip_runtime.h>

#define DIM 256
#define DIM4 (DIM / 4)

// ---------------------------------------------------------------------------
// 1) x = node_vectors * node_weight[:, None]
// ---------------------------------------------------------------------------
__global__ void compute_x_kernel(const float* __restrict__ nv,
                                 const float* __restrict__ w,
                                 float* __restrict__ x,
                                 int total4) {
    int i = blockIdx.x * blockDim.x + threadIdx.x;
    int stride = gridDim.x * blockDim.x;
    for (; i < total4; i += stride) {
        float4 v = reinterpret_cast<const float4*>(nv)[i];
        float wt = w[i / DIM4];
        v.x *= wt; v.y *= wt; v.z *= wt; v.w *= wt;
        reinterpret_cast<float4*>(x)[i] = v;
    }
}

// ---------------------------------------------------------------------------
// 2/4) dst[row[e]] += src[col[e]]   (COO scatter-add, one block per edge)
// ---------------------------------------------------------------------------
__global__ void scatter_add_kernel(const int* __restrict__ row,
                                   const int* __restrict__ col,
                                   const float* __restrict__ src,
                                   float* __restrict__ dst,
                                   int nedges) {
    int e = blockIdx.x;
    if (e >= nedges) return;
    int r = row[e];
    int c = col[e];
    int d = threadIdx.x;  // blockDim.x == DIM
    atomicAdd(&dst[(size_t)r * DIM + d], src[(size_t)c * DIM + d]);
}

// ---------------------------------------------------------------------------
// 3) deg[row[e]] += 1.0f
// ---------------------------------------------------------------------------
__global__ void deg_kernel(const int* __restrict__ row,
                           float* __restrict__ deg,
                           int nedges) {
    int e = blockIdx.x * blockDim.x + threadIdx.x;
    if (e < nedges) atomicAdd(&deg[row[e]], 1.0f);
}

// ---------------------------------------------------------------------------
// 5) per query edge: 4 dot products; one wave (64 lanes) per query
// ---------------------------------------------------------------------------
__device__ __forceinline__ float dot4(float4 a, float4 b) {
    return a.x * b.x + a.y * b.y + a.z * b.z + a.w * b.w;
}

__global__ void query_kernel(const int* __restrict__ es,
                             const int* __restrict__ et,
                             const float* __restrict__ x,
                             const float* __restrict__ oh,
                             const float* __restrict__ th,
                             const float* __restrict__ deg,
                             float* __restrict__ out,
                             int nq) {
    int gid = blockIdx.x * blockDim.x + threadIdx.x;
    int q = gid >> 6;          // one 64-lane wave per query
    int lane = gid & 63;
    if (q >= nq) return;

    int s = es[q];
    int t = et[q];

    const float4* xs  = reinterpret_cast<const float4*>(x  + (size_t)s * DIM);
    const float4* xt  = reinterpret_cast<const float4*>(x  + (size_t)t * DIM);
    const float4* ohs = reinterpret_cast<const float4*>(oh + (size_t)s * DIM);
    const float4* oht = reinterpret_cast<const float4*>(oh + (size_t)t * DIM);
    const float4* ths = reinterpret_cast<const float4*>(th + (size_t)s * DIM);
    const float4* tht = reinterpret_cast<const float4*>(th + (size_t)t * DIM);

    float4 vxs = xs[lane],  vxt = xt[lane];
    float4 vos = ohs[lane], vot = oht[lane];
    float4 vts = ths[lane], vtt = tht[lane];
    float ds = deg[s], dt = deg[t];

    // count_1_1
    float c11 = dot4(vos, vot);
    // count_1_2
    float c12 = dot4(vos, vtt) + dot4(vts, vot);
    // count_2_2 : (th_s - deg_s*x_s) . (th_t - deg_t*x_t)
    float4 a, b;
    a.x = vts.x - ds * vxs.x; a.y = vts.y - ds * vxs.y;
    a.z = vts.z - ds * vxs.z; a.w = vts.w - ds * vxs.w;
    b.x = vtt.x - dt * vxt.x; b.y = vtt.y - dt * vxt.y;
    b.z = vtt.z - dt * vxt.z; b.w = vtt.w - dt * vxt.w;
    float c22 = dot4(a, b);
    // count_self_1_2
    float cs = dot4(vos, vts) + dot4(vot, vtt);

    // wave reduction across 64 lanes
    #pragma unroll
    for (int off = 32; off > 0; off >>= 1) {
        c11 += __shfl_xor(c11, off);
        c12 += __shfl_xor(c12, off);
        c22 += __shfl_xor(c22, off);
        cs  += __shfl_xor(cs,  off);
    }

    if (lane == 0) {
        out[q]          = c11;
        out[nq + q]     = c12;
        out[2 * nq + q] = c22;
        out[3 * nq + q] = cs;
    }
}

// ---------------------------------------------------------------------------
extern "C" void kernel_launch(void* const* d_in, const int* in_sizes, int n_in,
                              void* d_out, int out_size, void* d_ws, size_t ws_size,
                              hipStream_t stream) {
    const int*   edges        = (const int*)  d_in[0];  // [2, EQ]
    const int*   adj_row      = (const int*)  d_in[1];  // [E]
    const int*   adj_col      = (const int*)  d_in[2];  // [E]
    const float* node_weight  = (const float*)d_in[3];  // [N]
    const float* node_vectors = (const float*)d_in[4];  // [N, DIM]

    const int EQ = in_sizes[0] / 2;
    const int E  = in_sizes[1];
    const int N  = in_sizes[3];

    float* x   = (float*)d_ws;                 // [N, DIM]
    float* oh  = x  + (size_t)N * DIM;         // [N, DIM]
    float* th  = oh + (size_t)N * DIM;         // [N, DIM]
    float* deg = th + (size_t)N * DIM;         // [N]

    const int* es = edges;
    const int* et = edges + EQ;

    float* out = (float*)d_out;

    // zero the accumulators (oh, th, deg are contiguous)
    hipMemsetAsync(oh, 0, ((size_t)2 * N * DIM + N) * sizeof(float), stream);

    // 1) x = nv * w
    int total4 = N * DIM4;
    compute_x_kernel<<<2048, 256, 0, stream>>>(node_vectors, node_weight, x, total4);

    // 2) one_hop scatter
    scatter_add_kernel<<<E, DIM, 0, stream>>>(adj_row, adj_col, x, oh, E);

    // 3) deg
    deg_kernel<<<(E + 255) / 256, 256, 0, stream>>>(adj_row, deg, E);

    // 4) two_hop scatter
    scatter_add_kernel<<<E, DIM, 0, stream>>>(adj_row, adj_col, oh, th, E);

    // 5) queries: one 64-lane wave per query
    int total_threads = EQ * 64;
    query_kernel<<<(total_threads + 255) / 256, 256, 0, stream>>>(
        es, et, x, oh, th, deg, out, EQ);
}

// Round 2
// 518.877 us; speedup vs baseline: 2.8226x; 2.8226x over previous
//
#include <hip/hip_runtime.h>

#define DIM 256
#define DIM4 (DIM / 4)

// ---------------------------------------------------------------------------
// 1) x = node_vectors * node_weight[:, None]
// ---------------------------------------------------------------------------
__global__ void compute_x_kernel(const float* __restrict__ nv,
                                 const float* __restrict__ w,
                                 float* __restrict__ x,
                                 int total4) {
    int i = blockIdx.x * blockDim.x + threadIdx.x;
    int stride = gridDim.x * blockDim.x;
    for (; i < total4; i += stride) {
        float4 v = reinterpret_cast<const float4*>(nv)[i];
        float wt = w[i / DIM4];
        v.x *= wt; v.y *= wt; v.z *= wt; v.w *= wt;
        reinterpret_cast<float4*>(x)[i] = v;
    }
}

// ---------------------------------------------------------------------------
// CSR build: histogram of adj_row
// ---------------------------------------------------------------------------
__global__ void hist_kernel(const int* __restrict__ row,
                            int* __restrict__ count,
                            int nedges) {
    int e = blockIdx.x * blockDim.x + threadIdx.x;
    if (e < nedges) atomicAdd(&count[row[e]], 1);
}

// ---------------------------------------------------------------------------
// Exclusive prefix sum of count[0..n) -> row_ptr[0..n]   (single block)
// ---------------------------------------------------------------------------
__global__ void scan_kernel(const int* __restrict__ count,
                            int* __restrict__ row_ptr,
                            int n) {
    __shared__ int lds[1024];
    __shared__ int running_s;
    if (threadIdx.x == 0) running_s = 0;
    __syncthreads();
    for (int base = 0; base < n; base += 1024) {
        int i = base + threadIdx.x;
        int v = (i < n) ? count[i] : 0;
        lds[threadIdx.x] = v;
        __syncthreads();
        #pragma unroll
        for (int off = 1; off < 1024; off <<= 1) {
            int tmp = (threadIdx.x >= off) ? lds[threadIdx.x - off] : 0;
            __syncthreads();
            lds[threadIdx.x] += tmp;
            __syncthreads();
        }
        int incl = lds[threadIdx.x];
        int running = running_s;
        if (i < n) row_ptr[i] = running + (incl - v);
        __syncthreads();
        if (threadIdx.x == 1023) running_s = running + lds[1023];
        __syncthreads();
    }
    if (threadIdx.x == 0) row_ptr[n] = running_s;
}

// ---------------------------------------------------------------------------
// cursor = row_ptr[0..n)
// ---------------------------------------------------------------------------
__global__ void copy_kernel(const int* __restrict__ src,
                            int* __restrict__ dst, int n) {
    int i = blockIdx.x * blockDim.x + threadIdx.x;
    if (i < n) dst[i] = src[i];
}

// ---------------------------------------------------------------------------
// perm[cursor[row[e]]++] = col[e]
// ---------------------------------------------------------------------------
__global__ void scatter_perm_kernel(const int* __restrict__ row,
                                    const int* __restrict__ col,
                                    int* __restrict__ cursor,
                                    int* __restrict__ perm,
                                    int nedges) {
    int e = blockIdx.x * blockDim.x + threadIdx.x;
    if (e < nedges) {
        int pos = atomicAdd(&cursor[row[e]], 1);
        perm[pos] = col[e];
    }
}

// ---------------------------------------------------------------------------
// Gather segment-sum: one 64-lane wave per row; lane holds float4 (4 dims)
// dst[r] = sum_{e in [row_ptr[r], row_ptr[r+1])} src[perm[e]]
// ---------------------------------------------------------------------------
__global__ void gather_hop_kernel(const int* __restrict__ row_ptr,
                                  const int* __restrict__ perm,
                                  const float* __restrict__ src,
                                  float* __restrict__ dst,
                                  int n) {
    int gid = blockIdx.x * blockDim.x + threadIdx.x;
    int r = gid >> 6;
    int lane = gid & 63;
    if (r >= n) return;
    int beg = row_ptr[r];
    int end = row_ptr[r + 1];
    float4 acc = make_float4(0.f, 0.f, 0.f, 0.f);
    for (int e = beg; e < end; ++e) {
        int c = perm[e];
        float4 v = reinterpret_cast<const float4*>(src)[(size_t)c * DIM4 + lane];
        acc.x += v.x; acc.y += v.y; acc.z += v.z; acc.w += v.w;
    }
    reinterpret_cast<float4*>(dst)[(size_t)r * DIM4 + lane] = acc;
}

// ---------------------------------------------------------------------------
// Query: 4 dot products per edge; one 64-lane wave per query
// ---------------------------------------------------------------------------
__device__ __forceinline__ float dot4(float4 a, float4 b) {
    return a.x * b.x + a.y * b.y + a.z * b.z + a.w * b.w;
}

__global__ void query_kernel(const int* __restrict__ es,
                             const int* __restrict__ et,
                             const float* __restrict__ x,
                             const float* __restrict__ oh,
                             const float* __restrict__ th,
                             const int* __restrict__ row_ptr,
                             float* __restrict__ out,
                             int nq) {
    int gid = blockIdx.x * blockDim.x + threadIdx.x;
    int q = gid >> 6;
    int lane = gid & 63;
    if (q >= nq) return;

    int s = es[q];
    int t = et[q];

    const float4* xs  = reinterpret_cast<const float4*>(x  + (size_t)s * DIM);
    const float4* xt  = reinterpret_cast<const float4*>(x  + (size_t)t * DIM);
    const float4* ohs = reinterpret_cast<const float4*>(oh + (size_t)s * DIM);
    const float4* oht = reinterpret_cast<const float4*>(oh + (size_t)t * DIM);
    const float4* ths = reinterpret_cast<const float4*>(th + (size_t)s * DIM);
    const float4* tht = reinterpret_cast<const float4*>(th + (size_t)t * DIM);

    float4 vxs = xs[lane],  vxt = xt[lane];
    float4 vos = ohs[lane], vot = oht[lane];
    float4 vts = ths[lane], vtt = tht[lane];
    float ds = (float)(row_ptr[s + 1] - row_ptr[s]);
    float dt = (float)(row_ptr[t + 1] - row_ptr[t]);

    float c11 = dot4(vos, vot);
    float c12 = dot4(vos, vtt) + dot4(vts, vot);
    float4 a, b;
    a.x = vts.x - ds * vxs.x; a.y = vts.y - ds * vxs.y;
    a.z = vts.z - ds * vxs.z; a.w = vts.w - ds * vxs.w;
    b.x = vtt.x - dt * vxt.x; b.y = vtt.y - dt * vxt.y;
    b.z = vtt.z - dt * vxt.z; b.w = vtt.w - dt * vxt.w;
    float c22 = dot4(a, b);
    float cs = dot4(vos, vts) + dot4(vot, vtt);

    #pragma unroll
    for (int off = 32; off > 0; off >>= 1) {
        c11 += __shfl_xor(c11, off);
        c12 += __shfl_xor(c12, off);
        c22 += __shfl_xor(c22, off);
        cs  += __shfl_xor(cs,  off);
    }

    if (lane == 0) {
        out[q]          = c11;
        out[nq + q]     = c12;
        out[2 * nq + q] = c22;
        out[3 * nq + q] = cs;
    }
}

// ---------------------------------------------------------------------------
extern "C" void kernel_launch(void* const* d_in, const int* in_sizes, int n_in,
                              void* d_out, int out_size, void* d_ws, size_t ws_size,
                              hipStream_t stream) {
    const int*   edges        = (const int*)  d_in[0];  // [2, EQ]
    const int*   adj_row      = (const int*)  d_in[1];  // [E]
    const int*   adj_col      = (const int*)  d_in[2];  // [E]
    const float* node_weight  = (const float*)d_in[3];  // [N]
    const float* node_vectors = (const float*)d_in[4];  // [N, DIM]

    const int EQ = in_sizes[0] / 2;
    const int E  = in_sizes[1];
    const int N  = in_sizes[3];

    // workspace layout
    float* x  = (float*)d_ws;                    // [N, DIM]
    float* oh = x  + (size_t)N * DIM;            // [N, DIM]
    float* th = oh + (size_t)N * DIM;            // [N, DIM]
    int* row_ptr = (int*)(th + (size_t)N * DIM); // [N+1]
    int* cursor  = row_ptr + (N + 1);            // [N]  (also histogram counts)
    int* perm    = cursor + N;                   // [E]

    const int* es = edges;
    const int* et = edges + EQ;
    float* out = (float*)d_out;

    // --- CSR build ---
    hipMemsetAsync(cursor, 0, (size_t)N * sizeof(int), stream);   // counts = 0
    hist_kernel<<<(E + 255) / 256, 256, 0, stream>>>(adj_row, cursor, E);
    scan_kernel<<<1, 1024, 0, stream>>>(cursor, row_ptr, N);
    copy_kernel<<<(N + 255) / 256, 256, 0, stream>>>(row_ptr, cursor, N);
    scatter_perm_kernel<<<(E + 255) / 256, 256, 0, stream>>>(adj_row, adj_col,
                                                             cursor, perm, E);

    // --- x = nv * w ---
    int total4 = N * DIM4;
    compute_x_kernel<<<2048, 256, 0, stream>>>(node_vectors, node_weight, x, total4);

    // --- one_hop / two_hop via gather ---
    int gthreads = N * 64;
    int gblocks = (gthreads + 255) / 256;
    gather_hop_kernel<<<gblocks, 256, 0, stream>>>(row_ptr, perm, x, oh, N);
    gather_hop_kernel<<<gblocks, 256, 0, stream>>>(row_ptr, perm, oh, th, N);

    // --- queries ---
    int qthreads = EQ * 64;
    query_kernel<<<(qthreads + 255) / 256, 256, 0, stream>>>(
        es, et, x, oh, th, row_ptr, out, EQ);
}

// Round 3
// 280.825 us; speedup vs baseline: 5.2153x; 1.8477x over previous
//
#include <hip/hip_runtime.h>

#define DIM 256
#define DIM4 (DIM / 4)
#define DIMU2 (DIM / 4)   // uint2 per row (4 bf16 per uint2) = 64

// ---- bf16 helpers (manual, RNE pack / exact unpack) -----------------------
__device__ __forceinline__ unsigned int f2bf_rne(float f) {
    unsigned int u = __float_as_uint(f);
    return (u + 0x7fffu + ((u >> 16) & 1u)) >> 16;   // round-to-nearest-even
}
__device__ __forceinline__ float bf_lo(unsigned int u) {
    return __uint_as_float(u << 16);
}
__device__ __forceinline__ float bf_hi(unsigned int u) {
    return __uint_as_float(u & 0xffff0000u);
}
__device__ __forceinline__ uint2 pack4(float a, float b, float c, float d) {
    uint2 r;
    r.x = f2bf_rne(a) | (f2bf_rne(b) << 16);
    r.y = f2bf_rne(c) | (f2bf_rne(d) << 16);
    return r;
}

// ---------------------------------------------------------------------------
// 1) xb = bf16(node_vectors * node_weight[:, None])
// ---------------------------------------------------------------------------
__global__ void compute_x_kernel(const float* __restrict__ nv,
                                 const float* __restrict__ w,
                                 uint2* __restrict__ xb,
                                 int total4) {
    int i = blockIdx.x * blockDim.x + threadIdx.x;
    int stride = gridDim.x * blockDim.x;
    for (; i < total4; i += stride) {
        float4 v = reinterpret_cast<const float4*>(nv)[i];
        float wt = w[i / DIM4];
        xb[i] = pack4(v.x * wt, v.y * wt, v.z * wt, v.w * wt);
    }
}

// ---------------------------------------------------------------------------
// CSR build
// ---------------------------------------------------------------------------
__global__ void hist_kernel(const int* __restrict__ row,
                            int* __restrict__ cnt, int nedges) {
    int e = blockIdx.x * blockDim.x + threadIdx.x;
    if (e < nedges) atomicAdd(&cnt[row[e]], 1);
}

__global__ void block_sum_kernel(const int* __restrict__ cnt,
                                 int* __restrict__ sums, int n) {
    __shared__ int lds[256];
    int i = blockIdx.x * 256 + threadIdx.x;
    lds[threadIdx.x] = (i < n) ? cnt[i] : 0;
    __syncthreads();
    #pragma unroll
    for (int off = 128; off > 0; off >>= 1) {
        if (threadIdx.x < off) lds[threadIdx.x] += lds[threadIdx.x + off];
        __syncthreads();
    }
    if (threadIdx.x == 0) sums[blockIdx.x] = lds[0];
}

// single block: exclusive-scan sums[0..nb), write total to row_ptr[n]
__global__ void scan_sums_kernel(int* __restrict__ sums, int nb,
                                 int* __restrict__ row_ptr_n) {
    __shared__ int lds[256];
    int v = (threadIdx.x < nb) ? sums[threadIdx.x] : 0;
    lds[threadIdx.x] = v;
    __syncthreads();
    #pragma unroll
    for (int off = 1; off < 256; off <<= 1) {
        int t = (threadIdx.x >= off) ? lds[threadIdx.x - off] : 0;
        __syncthreads();
        lds[threadIdx.x] += t;
        __syncthreads();
    }
    if (threadIdx.x < nb) sums[threadIdx.x] = lds[threadIdx.x] - v;  // exclusive
    if (threadIdx.x == 255) *row_ptr_n = lds[255];                   // total = E
}

__global__ void scan_block_kernel(const int* __restrict__ cnt,
                                  const int* __restrict__ sums,
                                  int* __restrict__ row_ptr,
                                  int* __restrict__ cursor, int n) {
    __shared__ int lds[256];
    int i = blockIdx.x * 256 + threadIdx.x;
    int v = (i < n) ? cnt[i] : 0;
    lds[threadIdx.x] = v;
    __syncthreads();
    #pragma unroll
    for (int off = 1; off < 256; off <<= 1) {
        int t = (threadIdx.x >= off) ? lds[threadIdx.x - off] : 0;
        __syncthreads();
        lds[threadIdx.x] += t;
        __syncthreads();
    }
    if (i < n) {
        int excl = sums[blockIdx.x] + lds[threadIdx.x] - v;
        row_ptr[i] = excl;
        cursor[i] = excl;
    }
}

__global__ void scatter_perm_kernel(const int* __restrict__ row,
                                    const int* __restrict__ col,
                                    int* __restrict__ cursor,
                                    int* __restrict__ perm, int nedges) {
    int e = blockIdx.x * blockDim.x + threadIdx.x;
    if (e < nedges) {
        int pos = atomicAdd(&cursor[row[e]], 1);
        perm[pos] = col[e];
    }
}

// ---------------------------------------------------------------------------
// Gather segment-sum over bf16 rows: one 64-lane wave per row.
// Each lane handles 4 dims (one uint2 = 4 bf16). fp32 accumulate, bf16 store.
// ---------------------------------------------------------------------------
__global__ void gather_hop_kernel(const int* __restrict__ row_ptr,
                                  const int* __restrict__ perm,
                                  const uint2* __restrict__ src,
                                  uint2* __restrict__ dst, int n) {
    int gid = blockIdx.x * blockDim.x + threadIdx.x;
    int r = gid >> 6;
    int lane = gid & 63;
    if (r >= n) return;
    int beg = row_ptr[r];
    int end = row_ptr[r + 1];
    float a0 = 0.f, a1 = 0.f, a2 = 0.f, a3 = 0.f;
    int e = beg;
    for (; e + 2 <= end; e += 2) {
        int c0 = perm[e];
        int c1 = perm[e + 1];
        uint2 v0 = src[(size_t)c0 * DIMU2 + lane];
        uint2 v1 = src[(size_t)c1 * DIMU2 + lane];
        a0 += bf_lo(v0.x); a1 += bf_hi(v0.x);
        a2 += bf_lo(v0.y); a3 += bf_hi(v0.y);
        a0 += bf_lo(v1.x); a1 += bf_hi(v1.x);
        a2 += bf_lo(v1.y); a3 += bf_hi(v1.y);
    }
    if (e < end) {
        int c0 = perm[e];
        uint2 v0 = src[(size_t)c0 * DIMU2 + lane];
        a0 += bf_lo(v0.x); a1 += bf_hi(v0.x);
        a2 += bf_lo(v0.y); a3 += bf_hi(v0.y);
    }
    dst[(size_t)r * DIMU2 + lane] = pack4(a0, a1, a2, a3);
}

// ---------------------------------------------------------------------------
// Query: 4 dot products per edge; one 64-lane wave per query (bf16 reads)
// ---------------------------------------------------------------------------
__global__ void query_kernel(const int* __restrict__ es,
                             const int* __restrict__ et,
                             const uint2* __restrict__ xb,
                             const uint2* __restrict__ ohb,
                             const uint2* __restrict__ thb,
                             const int* __restrict__ row_ptr,
                             float* __restrict__ out, int nq) {
    int gid = blockIdx.x * blockDim.x + threadIdx.x;
    int q = gid >> 6;
    int lane = gid & 63;
    if (q >= nq) return;

    int s = es[q];
    int t = et[q];

    uint2 vxs = xb [(size_t)s * DIMU2 + lane];
    uint2 vxt = xb [(size_t)t * DIMU2 + lane];
    uint2 vos = ohb[(size_t)s * DIMU2 + lane];
    uint2 vot = ohb[(size_t)t * DIMU2 + lane];
    uint2 vts = thb[(size_t)s * DIMU2 + lane];
    uint2 vtt = thb[(size_t)t * DIMU2 + lane];
    float ds = (float)(row_ptr[s + 1] - row_ptr[s]);
    float dt = (float)(row_ptr[t + 1] - row_ptr[t]);

    float c11 = 0.f, c12 = 0.f, c22 = 0.f, cs = 0.f;
    #pragma unroll
    for (int k = 0; k < 4; ++k) {
        float fxs, fxt, fos, fot, fts, ftt;
        switch (k) {
            case 0: fxs = bf_lo(vxs.x); fxt = bf_lo(vxt.x); fos = bf_lo(vos.x);
                    fot = bf_lo(vot.x); fts = bf_lo(vts.x); ftt = bf_lo(vtt.x); break;
            case 1: fxs = bf_hi(vxs.x); fxt = bf_hi(vxt.x); fos = bf_hi(vos.x);
                    fot = bf_hi(vot.x); fts = bf_hi(vts.x); ftt = bf_hi(vtt.x); break;
            case 2: fxs = bf_lo(vxs.y); fxt = bf_lo(vxt.y); fos = bf_lo(vos.y);
                    fot = bf_lo(vot.y); fts = bf_lo(vts.y); ftt = bf_lo(vtt.y); break;
            default:fxs = bf_hi(vxs.y); fxt = bf_hi(vxt.y); fos = bf_hi(vos.y);
                    fot = bf_hi(vot.y); fts = bf_hi(vts.y); ftt = bf_hi(vtt.y); break;
        }
        c11 += fos * fot;
        c12 += fos * ftt + fts * fot;
        float as = fts - ds * fxs;
        float bt = ftt - dt * fxt;
        c22 += as * bt;
        cs  += fos * fts + fot * ftt;
    }

    #pragma unroll
    for (int off = 32; off > 0; off >>= 1) {
        c11 += __shfl_xor(c11, off);
        c12 += __shfl_xor(c12, off);
        c22 += __shfl_xor(c22, off);
        cs  += __shfl_xor(cs,  off);
    }

    if (lane == 0) {
        out[q]          = c11;
        out[nq + q]     = c12;
        out[2 * nq + q] = c22;
        out[3 * nq + q] = cs;
    }
}

// ---------------------------------------------------------------------------
extern "C" void kernel_launch(void* const* d_in, const int* in_sizes, int n_in,
                              void* d_out, int out_size, void* d_ws, size_t ws_size,
                              hipStream_t stream) {
    const int*   edges        = (const int*)  d_in[0];  // [2, EQ]
    const int*   adj_row      = (const int*)  d_in[1];  // [E]
    const int*   adj_col      = (const int*)  d_in[2];  // [E]
    const float* node_weight  = (const float*)d_in[3];  // [N]
    const float* node_vectors = (const float*)d_in[4];  // [N, DIM]

    const int EQ = in_sizes[0] / 2;
    const int E  = in_sizes[1];
    const int N  = in_sizes[3];

    // workspace layout (bf16 rows stored as uint2[N*64])
    uint2* xb  = (uint2*)d_ws;                 // N*64 uint2 = 25.6 MB
    uint2* ohb = xb  + (size_t)N * DIMU2;
    uint2* thb = ohb + (size_t)N * DIMU2;
    int* row_ptr = (int*)(thb + (size_t)N * DIMU2);  // [N+1]
    int* cursor  = row_ptr + (N + 1);                // [N]
    int* cnt     = cursor + N;                       // [N]
    int* perm    = cnt + N;                          // [E]
    int* sums    = perm + E;                         // [<=256]

    const int* es = edges;
    const int* et = edges + EQ;
    float* out = (float*)d_out;

    int nb = (N + 255) / 256;

    // --- CSR build ---
    hipMemsetAsync(cnt, 0, (size_t)N * sizeof(int), stream);
    hist_kernel<<<(E + 255) / 256, 256, 0, stream>>>(adj_row, cnt, E);
    block_sum_kernel<<<nb, 256, 0, stream>>>(cnt, sums, N);
    scan_sums_kernel<<<1, 256, 0, stream>>>(sums, nb, row_ptr + N);
    scan_block_kernel<<<nb, 256, 0, stream>>>(cnt, sums, row_ptr, cursor, N);
    scatter_perm_kernel<<<(E + 255) / 256, 256, 0, stream>>>(adj_row, adj_col,
                                                             cursor, perm, E);

    // --- x = bf16(nv * w) ---
    int total4 = N * DIM4;
    compute_x_kernel<<<2048, 256, 0, stream>>>(node_vectors, node_weight, xb, total4);

    // --- one_hop / two_hop via gather ---
    int gthreads = N * 64;
    int gblocks = (gthreads + 255) / 256;
    gather_hop_kernel<<<gblocks, 256, 0, stream>>>(row_ptr, perm, xb, ohb, N);
    gather_hop_kernel<<<gblocks, 256, 0, stream>>>(row_ptr, perm, ohb, thb, N);

    // --- queries ---
    int qthreads = EQ * 64;
    query_kernel<<<(qthreads + 255) / 256, 256, 0, stream>>>(
        es, et, xb, ohb, thb, row_ptr, out, EQ);
}

// Round 4
// 271.108 us; speedup vs baseline: 5.4022x; 1.0358x over previous
//
#include <hip/hip_runtime.h>

#define DIM 256
// combined layout: per node 3 slots (x, oh, th), each 256 bf16 = 512 B
// node stride: 1536 B = 192 uint2 = 96 uint4
#define NODE_U2 192
#define NODE_U4 96
#define SLOT_OH_U2 64
#define SLOT_TH_U2 128
#define SLOT_OH_U4 32
#define SLOT_TH_U4 64

// ---- bf16 helpers (manual, RNE pack / exact unpack) -----------------------
__device__ __forceinline__ unsigned int f2bf_rne(float f) {
    unsigned int u = __float_as_uint(f);
    return (u + 0x7fffu + ((u >> 16) & 1u)) >> 16;
}
__device__ __forceinline__ float bf_lo(unsigned int u) {
    return __uint_as_float(u << 16);
}
__device__ __forceinline__ float bf_hi(unsigned int u) {
    return __uint_as_float(u & 0xffff0000u);
}
__device__ __forceinline__ unsigned int pack2(float a, float b) {
    return f2bf_rne(a) | (f2bf_rne(b) << 16);
}

// ---------------------------------------------------------------------------
// 1) combined[node][slot x] = bf16(nv * w)
// ---------------------------------------------------------------------------
__global__ void compute_x_kernel(const float* __restrict__ nv,
                                 const float* __restrict__ w,
                                 uint2* __restrict__ cmb,
                                 int total_u2) {   // N*64
    int i = blockIdx.x * blockDim.x + threadIdx.x;
    int stride = gridDim.x * blockDim.x;
    for (; i < total_u2; i += stride) {
        float4 v = reinterpret_cast<const float4*>(nv)[i];
        int node = i >> 6;
        int j = i & 63;
        float wt = w[node];
        uint2 r;
        r.x = pack2(v.x * wt, v.y * wt);
        r.y = pack2(v.z * wt, v.w * wt);
        cmb[(size_t)node * NODE_U2 + j] = r;
    }
}

// ---------------------------------------------------------------------------
// CSR build
// ---------------------------------------------------------------------------
__global__ void hist_kernel(const int* __restrict__ row,
                            int* __restrict__ cnt, int nedges) {
    int e = blockIdx.x * blockDim.x + threadIdx.x;
    if (e < nedges) atomicAdd(&cnt[row[e]], 1);
}

__global__ void block_sum_kernel(const int* __restrict__ cnt,
                                 int* __restrict__ sums, int n) {
    __shared__ int lds[256];
    int i = blockIdx.x * 256 + threadIdx.x;
    lds[threadIdx.x] = (i < n) ? cnt[i] : 0;
    __syncthreads();
    #pragma unroll
    for (int off = 128; off > 0; off >>= 1) {
        if (threadIdx.x < off) lds[threadIdx.x] += lds[threadIdx.x + off];
        __syncthreads();
    }
    if (threadIdx.x == 0) sums[blockIdx.x] = lds[0];
}

__global__ void scan_sums_kernel(int* __restrict__ sums, int nb,
                                 int* __restrict__ row_ptr_n) {
    __shared__ int lds[256];
    int v = (threadIdx.x < nb) ? sums[threadIdx.x] : 0;
    lds[threadIdx.x] = v;
    __syncthreads();
    #pragma unroll
    for (int off = 1; off < 256; off <<= 1) {
        int t = (threadIdx.x >= off) ? lds[threadIdx.x - off] : 0;
        __syncthreads();
        lds[threadIdx.x] += t;
        __syncthreads();
    }
    if (threadIdx.x < nb) sums[threadIdx.x] = lds[threadIdx.x] - v;
    if (threadIdx.x == 255) *row_ptr_n = lds[255];
}

__global__ void scan_block_kernel(const int* __restrict__ cnt,
                                  const int* __restrict__ sums,
                                  int* __restrict__ row_ptr,
                                  int* __restrict__ cursor, int n) {
    __shared__ int lds[256];
    int i = blockIdx.x * 256 + threadIdx.x;
    int v = (i < n) ? cnt[i] : 0;
    lds[threadIdx.x] = v;
    __syncthreads();
    #pragma unroll
    for (int off = 1; off < 256; off <<= 1) {
        int t = (threadIdx.x >= off) ? lds[threadIdx.x - off] : 0;
        __syncthreads();
        lds[threadIdx.x] += t;
        __syncthreads();
    }
    if (i < n) {
        int excl = sums[blockIdx.x] + lds[threadIdx.x] - v;
        row_ptr[i] = excl;
        cursor[i] = excl;
    }
}

__global__ void scatter_perm_kernel(const int* __restrict__ row,
                                    const int* __restrict__ col,
                                    int* __restrict__ cursor,
                                    int* __restrict__ perm, int nedges) {
    int e = blockIdx.x * blockDim.x + threadIdx.x;
    if (e < nedges) {
        int pos = atomicAdd(&cursor[row[e]], 1);
        perm[pos] = col[e];
    }
}

// ---------------------------------------------------------------------------
// Gather segment-sum, uint4 lanes: one wave per row; lanes 0-31 walk edges
// beg,beg+2,..., lanes 32-63 walk beg+1,beg+3,...  Each lane loads 16B
// (8 bf16 dims). Cross-half shfl reduce, lanes 0-31 store the 512B row.
// src/dst point at the slot base inside the combined array (stride NODE_U4).
// ---------------------------------------------------------------------------
__global__ void gather_hop_kernel(const int* __restrict__ row_ptr,
                                  const int* __restrict__ perm,
                                  const uint4* __restrict__ src,
                                  uint4* __restrict__ dst, int n) {
    int gid = blockIdx.x * blockDim.x + threadIdx.x;
    int r = gid >> 6;
    if (r >= n) return;
    int lane = gid & 63;
    int h = lane >> 5;      // which half-wave
    int l = lane & 31;      // uint4 index within row

    int beg = row_ptr[r];
    int end = row_ptr[r + 1];

    float a0 = 0.f, a1 = 0.f, a2 = 0.f, a3 = 0.f;
    float a4 = 0.f, a5 = 0.f, a6 = 0.f, a7 = 0.f;

    int e = beg + h;
    // two edges per half-wave in flight (4 per wave)
    while (e + 2 < end) {
        int c0 = perm[e];
        int c1 = perm[e + 2];
        uint4 v0 = src[(size_t)c0 * NODE_U4 + l];
        uint4 v1 = src[(size_t)c1 * NODE_U4 + l];
        a0 += bf_lo(v0.x); a1 += bf_hi(v0.x);
        a2 += bf_lo(v0.y); a3 += bf_hi(v0.y);
        a4 += bf_lo(v0.z); a5 += bf_hi(v0.z);
        a6 += bf_lo(v0.w); a7 += bf_hi(v0.w);
        a0 += bf_lo(v1.x); a1 += bf_hi(v1.x);
        a2 += bf_lo(v1.y); a3 += bf_hi(v1.y);
        a4 += bf_lo(v1.z); a5 += bf_hi(v1.z);
        a6 += bf_lo(v1.w); a7 += bf_hi(v1.w);
        e += 4;
    }
    if (e < end) {
        int c0 = perm[e];
        uint4 v0 = src[(size_t)c0 * NODE_U4 + l];
        a0 += bf_lo(v0.x); a1 += bf_hi(v0.x);
        a2 += bf_lo(v0.y); a3 += bf_hi(v0.y);
        a4 += bf_lo(v0.z); a5 += bf_hi(v0.z);
        a6 += bf_lo(v0.w); a7 += bf_hi(v0.w);
    }

    // combine halves
    a0 += __shfl_xor(a0, 32); a1 += __shfl_xor(a1, 32);
    a2 += __shfl_xor(a2, 32); a3 += __shfl_xor(a3, 32);
    a4 += __shfl_xor(a4, 32); a5 += __shfl_xor(a5, 32);
    a6 += __shfl_xor(a6, 32); a7 += __shfl_xor(a7, 32);

    if (lane < 32) {
        uint4 o;
        o.x = pack2(a0, a1);
        o.y = pack2(a2, a3);
        o.z = pack2(a4, a5);
        o.w = pack2(a6, a7);
        dst[(size_t)r * NODE_U4 + l] = o;
    }
}

// ---------------------------------------------------------------------------
// Query: one 64-lane wave per query; per node the 3 slots are contiguous.
// ---------------------------------------------------------------------------
__global__ void query_kernel(const int* __restrict__ es,
                             const int* __restrict__ et,
                             const uint2* __restrict__ cmb,
                             const int* __restrict__ row_ptr,
                             float* __restrict__ out, int nq) {
    int gid = blockIdx.x * blockDim.x + threadIdx.x;
    int q = gid >> 6;
    if (q >= nq) return;
    int lane = gid & 63;

    int s = es[q];
    int t = et[q];

    const uint2* ns = cmb + (size_t)s * NODE_U2;
    const uint2* nt = cmb + (size_t)t * NODE_U2;

    uint2 vxs = ns[lane];
    uint2 vos = ns[SLOT_OH_U2 + lane];
    uint2 vts = ns[SLOT_TH_U2 + lane];
    uint2 vxt = nt[lane];
    uint2 vot = nt[SLOT_OH_U2 + lane];
    uint2 vtt = nt[SLOT_TH_U2 + lane];
    float ds = (float)(row_ptr[s + 1] - row_ptr[s]);
    float dt = (float)(row_ptr[t + 1] - row_ptr[t]);

    float c11 = 0.f, c12 = 0.f, c22 = 0.f, cs = 0.f;
    #pragma unroll
    for (int k = 0; k < 4; ++k) {
        float fxs, fxt, fos, fot, fts, ftt;
        switch (k) {
            case 0: fxs = bf_lo(vxs.x); fxt = bf_lo(vxt.x); fos = bf_lo(vos.x);
                    fot = bf_lo(vot.x); fts = bf_lo(vts.x); ftt = bf_lo(vtt.x); break;
            case 1: fxs = bf_hi(vxs.x); fxt = bf_hi(vxt.x); fos = bf_hi(vos.x);
                    fot = bf_hi(vot.x); fts = bf_hi(vts.x); ftt = bf_hi(vtt.x); break;
            case 2: fxs = bf_lo(vxs.y); fxt = bf_lo(vxt.y); fos = bf_lo(vos.y);
                    fot = bf_lo(vot.y); fts = bf_lo(vts.y); ftt = bf_lo(vtt.y); break;
            default:fxs = bf_hi(vxs.y); fxt = bf_hi(vxt.y); fos = bf_hi(vos.y);
                    fot = bf_hi(vot.y); fts = bf_hi(vts.y); ftt = bf_hi(vtt.y); break;
        }
        c11 += fos * fot;
        c12 += fos * ftt + fts * fot;
        float as = fts - ds * fxs;
        float bt = ftt - dt * fxt;
        c22 += as * bt;
        cs  += fos * fts + fot * ftt;
    }

    #pragma unroll
    for (int off = 32; off > 0; off >>= 1) {
        c11 += __shfl_xor(c11, off);
        c12 += __shfl_xor(c12, off);
        c22 += __shfl_xor(c22, off);
        cs  += __shfl_xor(cs,  off);
    }

    if (lane == 0) {
        out[q]          = c11;
        out[nq + q]     = c12;
        out[2 * nq + q] = c22;
        out[3 * nq + q] = cs;
    }
}

// ---------------------------------------------------------------------------
extern "C" void kernel_launch(void* const* d_in, const int* in_sizes, int n_in,
                              void* d_out, int out_size, void* d_ws, size_t ws_size,
                              hipStream_t stream) {
    const int*   edges        = (const int*)  d_in[0];  // [2, EQ]
    const int*   adj_row      = (const int*)  d_in[1];  // [E]
    const int*   adj_col      = (const int*)  d_in[2];  // [E]
    const float* node_weight  = (const float*)d_in[3];  // [N]
    const float* node_vectors = (const float*)d_in[4];  // [N, DIM]

    const int EQ = in_sizes[0] / 2;
    const int E  = in_sizes[1];
    const int N  = in_sizes[3];

    // workspace: combined bf16 [N][3][256] then CSR arrays
    uint2* cmb = (uint2*)d_ws;                          // N * 192 uint2 = 76.8 MB
    int* row_ptr = (int*)(cmb + (size_t)N * NODE_U2);   // [N+1]
    int* cursor  = row_ptr + (N + 1);                   // [N]
    int* cnt     = cursor + N;                          // [N]
    int* perm    = cnt + N;                             // [E]
    int* sums    = perm + E;                            // [<=256]

    const int* es = edges;
    const int* et = edges + EQ;
    float* out = (float*)d_out;

    int nb = (N + 255) / 256;

    // --- CSR build ---
    hipMemsetAsync(cnt, 0, (size_t)N * sizeof(int), stream);
    hist_kernel<<<(E + 255) / 256, 256, 0, stream>>>(adj_row, cnt, E);
    block_sum_kernel<<<nb, 256, 0, stream>>>(cnt, sums, N);
    scan_sums_kernel<<<1, 256, 0, stream>>>(sums, nb, row_ptr + N);
    scan_block_kernel<<<nb, 256, 0, stream>>>(cnt, sums, row_ptr, cursor, N);
    scatter_perm_kernel<<<(E + 255) / 256, 256, 0, stream>>>(adj_row, adj_col,
                                                             cursor, perm, E);

    // --- x slot ---
    int total_u2 = N * 64;
    compute_x_kernel<<<2048, 256, 0, stream>>>(node_vectors, node_weight, cmb,
                                               total_u2);

    // --- one_hop / two_hop via uint4 gather ---
    const uint4* cmb4 = (const uint4*)cmb;
    int gthreads = N * 64;
    int gblocks = (gthreads + 255) / 256;
    gather_hop_kernel<<<gblocks, 256, 0, stream>>>(
        row_ptr, perm, cmb4, (uint4*)cmb4 + SLOT_OH_U4, N);
    gather_hop_kernel<<<gblocks, 256, 0, stream>>>(
        row_ptr, perm, cmb4 + SLOT_OH_U4, (uint4*)cmb4 + SLOT_TH_U4, N);

    // --- queries ---
    int qthreads = EQ * 64;
    query_kernel<<<(qthreads + 255) / 256, 256, 0, stream>>>(
        es, et, cmb, row_ptr, out, EQ);
}

// Round 5
// 270.938 us; speedup vs baseline: 5.4056x; 1.0006x over previous
//
#include <hip/hip_runtime.h>

#define DIM 256
// combined layout: per node 3 slots (x, oh, th), each 256 bf16 = 512 B
// node stride: 1536 B = 192 uint2 = 96 uint4
#define NODE_U2 192
#define NODE_U4 96
#define SLOT_OH_U2 64
#define SLOT_TH_U2 128
#define SLOT_OH_U4 32
#define SLOT_TH_U4 64

// ---- bf16 helpers (manual, RNE pack / exact unpack) -----------------------
__device__ __forceinline__ unsigned int f2bf_rne(float f) {
    unsigned int u = __float_as_uint(f);
    return (u + 0x7fffu + ((u >> 16) & 1u)) >> 16;
}
__device__ __forceinline__ float bf_lo(unsigned int u) {
    return __uint_as_float(u << 16);
}
__device__ __forceinline__ float bf_hi(unsigned int u) {
    return __uint_as_float(u & 0xffff0000u);
}
__device__ __forceinline__ unsigned int pack2(float a, float b) {
    return f2bf_rne(a) | (f2bf_rne(b) << 16);
}

#define ACC8(v)                                            \
    do {                                                   \
        a0 += bf_lo((v).x); a1 += bf_hi((v).x);            \
        a2 += bf_lo((v).y); a3 += bf_hi((v).y);            \
        a4 += bf_lo((v).z); a5 += bf_hi((v).z);            \
        a6 += bf_lo((v).w); a7 += bf_hi((v).w);            \
    } while (0)

// ---------------------------------------------------------------------------
// 1) combined[node][slot x] = bf16(nv * w)
// ---------------------------------------------------------------------------
__global__ void compute_x_kernel(const float* __restrict__ nv,
                                 const float* __restrict__ w,
                                 uint2* __restrict__ cmb,
                                 int total_u2) {   // N*64
    int i = blockIdx.x * blockDim.x + threadIdx.x;
    int stride = gridDim.x * blockDim.x;
    for (; i < total_u2; i += stride) {
        float4 v = reinterpret_cast<const float4*>(nv)[i];
        int node = i >> 6;
        int j = i & 63;
        float wt = w[node];
        uint2 r;
        r.x = pack2(v.x * wt, v.y * wt);
        r.y = pack2(v.z * wt, v.w * wt);
        cmb[(size_t)node * NODE_U2 + j] = r;
    }
}

// ---------------------------------------------------------------------------
// CSR build
// ---------------------------------------------------------------------------
__global__ void hist_kernel(const int* __restrict__ row,
                            int* __restrict__ cnt, int nedges) {
    int e = blockIdx.x * blockDim.x + threadIdx.x;
    if (e < nedges) atomicAdd(&cnt[row[e]], 1);
}

__global__ void block_sum_kernel(const int* __restrict__ cnt,
                                 int* __restrict__ sums, int n) {
    __shared__ int lds[256];
    int i = blockIdx.x * 256 + threadIdx.x;
    lds[threadIdx.x] = (i < n) ? cnt[i] : 0;
    __syncthreads();
    #pragma unroll
    for (int off = 128; off > 0; off >>= 1) {
        if (threadIdx.x < off) lds[threadIdx.x] += lds[threadIdx.x + off];
        __syncthreads();
    }
    if (threadIdx.x == 0) sums[blockIdx.x] = lds[0];
}

__global__ void scan_sums_kernel(int* __restrict__ sums, int nb,
                                 int* __restrict__ row_ptr_n) {
    __shared__ int lds[256];
    int v = (threadIdx.x < nb) ? sums[threadIdx.x] : 0;
    lds[threadIdx.x] = v;
    __syncthreads();
    #pragma unroll
    for (int off = 1; off < 256; off <<= 1) {
        int t = (threadIdx.x >= off) ? lds[threadIdx.x - off] : 0;
        __syncthreads();
        lds[threadIdx.x] += t;
        __syncthreads();
    }
    if (threadIdx.x < nb) sums[threadIdx.x] = lds[threadIdx.x] - v;
    if (threadIdx.x == 255) *row_ptr_n = lds[255];
}

__global__ void scan_block_kernel(const int* __restrict__ cnt,
                                  const int* __restrict__ sums,
                                  int* __restrict__ row_ptr,
                                  int* __restrict__ cursor, int n) {
    __shared__ int lds[256];
    int i = blockIdx.x * 256 + threadIdx.x;
    int v = (i < n) ? cnt[i] : 0;
    lds[threadIdx.x] = v;
    __syncthreads();
    #pragma unroll
    for (int off = 1; off < 256; off <<= 1) {
        int t = (threadIdx.x >= off) ? lds[threadIdx.x - off] : 0;
        __syncthreads();
        lds[threadIdx.x] += t;
        __syncthreads();
    }
    if (i < n) {
        int excl = sums[blockIdx.x] + lds[threadIdx.x] - v;
        row_ptr[i] = excl;
        cursor[i] = excl;
    }
}

__global__ void scatter_perm_kernel(const int* __restrict__ row,
                                    const int* __restrict__ col,
                                    int* __restrict__ cursor,
                                    int* __restrict__ perm, int nedges) {
    int e = blockIdx.x * blockDim.x + threadIdx.x;
    if (e < nedges) {
        int pos = atomicAdd(&cursor[row[e]], 1);
        perm[pos] = col[e];
    }
}

// ---------------------------------------------------------------------------
// Gather segment-sum, one wave per row. Lanes 0-31 walk edges beg,beg+2,...,
// lanes 32-63 walk beg+1,beg+3,...  Main loop: 4 edges per half in flight
// (8 row-loads per wave). Cross-half shfl reduce, lanes 0-31 store the row.
// src/dst point at the slot base inside the combined array (stride NODE_U4).
// ---------------------------------------------------------------------------
__global__ void gather_hop_kernel(const int* __restrict__ row_ptr,
                                  const int* __restrict__ perm,
                                  const uint4* __restrict__ src,
                                  uint4* __restrict__ dst, int n) {
    int gid = blockIdx.x * blockDim.x + threadIdx.x;
    int r = gid >> 6;
    if (r >= n) return;
    int lane = gid & 63;
    int h = lane >> 5;      // which half-wave
    int l = lane & 31;      // uint4 index within row

    int beg = row_ptr[r];
    int end = row_ptr[r + 1];

    float a0 = 0.f, a1 = 0.f, a2 = 0.f, a3 = 0.f;
    float a4 = 0.f, a5 = 0.f, a6 = 0.f, a7 = 0.f;

    int e = beg + h;
    // 4 edges per half per iteration: e, e+2, e+4, e+6 (8 loads/wave in flight)
    while (e + 6 < end) {
        int c0 = perm[e];
        int c1 = perm[e + 2];
        int c2 = perm[e + 4];
        int c3 = perm[e + 6];
        uint4 v0 = src[(size_t)c0 * NODE_U4 + l];
        uint4 v1 = src[(size_t)c1 * NODE_U4 + l];
        uint4 v2 = src[(size_t)c2 * NODE_U4 + l];
        uint4 v3 = src[(size_t)c3 * NODE_U4 + l];
        ACC8(v0); ACC8(v1); ACC8(v2); ACC8(v3);
        e += 8;
    }
    while (e < end) {
        int c0 = perm[e];
        uint4 v0 = src[(size_t)c0 * NODE_U4 + l];
        ACC8(v0);
        e += 2;
    }

    // combine halves
    a0 += __shfl_xor(a0, 32); a1 += __shfl_xor(a1, 32);
    a2 += __shfl_xor(a2, 32); a3 += __shfl_xor(a3, 32);
    a4 += __shfl_xor(a4, 32); a5 += __shfl_xor(a5, 32);
    a6 += __shfl_xor(a6, 32); a7 += __shfl_xor(a7, 32);

    if (lane < 32) {
        uint4 o;
        o.x = pack2(a0, a1);
        o.y = pack2(a2, a3);
        o.z = pack2(a4, a5);
        o.w = pack2(a6, a7);
        dst[(size_t)r * NODE_U4 + l] = o;
    }
}

// ---------------------------------------------------------------------------
// Query: 32 lanes per query (uint4 loads), 2 queries per wave.
// ---------------------------------------------------------------------------
__global__ void query_kernel(const int* __restrict__ es,
                             const int* __restrict__ et,
                             const uint4* __restrict__ cmb4,
                             const int* __restrict__ row_ptr,
                             float* __restrict__ out, int nq) {
    int gid = blockIdx.x * blockDim.x + threadIdx.x;
    int q = gid >> 5;
    if (q >= nq) return;
    int l = gid & 31;

    int s = es[q];
    int t = et[q];

    const uint4* ns = cmb4 + (size_t)s * NODE_U4;
    const uint4* nt = cmb4 + (size_t)t * NODE_U4;

    uint4 vxs = ns[l];
    uint4 vos = ns[SLOT_OH_U4 + l];
    uint4 vts = ns[SLOT_TH_U4 + l];
    uint4 vxt = nt[l];
    uint4 vot = nt[SLOT_OH_U4 + l];
    uint4 vtt = nt[SLOT_TH_U4 + l];
    float ds = (float)(row_ptr[s + 1] - row_ptr[s]);
    float dt = (float)(row_ptr[t + 1] - row_ptr[t]);

    float c11 = 0.f, c12 = 0.f, c22 = 0.f, cs = 0.f;
    const unsigned int* pxs = (const unsigned int*)&vxs;
    const unsigned int* pxt = (const unsigned int*)&vxt;
    const unsigned int* pos_ = (const unsigned int*)&vos;
    const unsigned int* pot = (const unsigned int*)&vot;
    const unsigned int* pts = (const unsigned int*)&vts;
    const unsigned int* ptt = (const unsigned int*)&vtt;
    #pragma unroll
    for (int k = 0; k < 4; ++k) {
        // low half
        {
            float fxs = bf_lo(pxs[k]), fxt = bf_lo(pxt[k]);
            float fos = bf_lo(pos_[k]), fot = bf_lo(pot[k]);
            float fts = bf_lo(pts[k]), ftt = bf_lo(ptt[k]);
            c11 += fos * fot;
            c12 += fos * ftt + fts * fot;
            float as = fts - ds * fxs;
            float bt = ftt - dt * fxt;
            c22 += as * bt;
            cs  += fos * fts + fot * ftt;
        }
        // high half
        {
            float fxs = bf_hi(pxs[k]), fxt = bf_hi(pxt[k]);
            float fos = bf_hi(pos_[k]), fot = bf_hi(pot[k]);
            float fts = bf_hi(pts[k]), ftt = bf_hi(ptt[k]);
            c11 += fos * fot;
            c12 += fos * ftt + fts * fot;
            float as = fts - ds * fxs;
            float bt = ftt - dt * fxt;
            c22 += as * bt;
            cs  += fos * fts + fot * ftt;
        }
    }

    // reduce within 32-lane group (xor masks < 32 stay in-group)
    #pragma unroll
    for (int off = 16; off > 0; off >>= 1) {
        c11 += __shfl_xor(c11, off);
        c12 += __shfl_xor(c12, off);
        c22 += __shfl_xor(c22, off);
        cs  += __shfl_xor(cs,  off);
    }

    if (l == 0) {
        out[q]          = c11;
        out[nq + q]     = c12;
        out[2 * nq + q] = c22;
        out[3 * nq + q] = cs;
    }
}

// ---------------------------------------------------------------------------
extern "C" void kernel_launch(void* const* d_in, const int* in_sizes, int n_in,
                              void* d_out, int out_size, void* d_ws, size_t ws_size,
                              hipStream_t stream) {
    const int*   edges        = (const int*)  d_in[0];  // [2, EQ]
    const int*   adj_row      = (const int*)  d_in[1];  // [E]
    const int*   adj_col      = (const int*)  d_in[2];  // [E]
    const float* node_weight  = (const float*)d_in[3];  // [N]
    const float* node_vectors = (const float*)d_in[4];  // [N, DIM]

    const int EQ = in_sizes[0] / 2;
    const int E  = in_sizes[1];
    const int N  = in_sizes[3];

    // workspace: combined bf16 [N][3][256] then CSR arrays
    uint2* cmb = (uint2*)d_ws;                          // N * 192 uint2 = 76.8 MB
    int* row_ptr = (int*)(cmb + (size_t)N * NODE_U2);   // [N+1]
    int* cursor  = row_ptr + (N + 1);                   // [N]
    int* cnt     = cursor + N;                          // [N]
    int* perm    = cnt + N;                             // [E]
    int* sums    = perm + E;                            // [<=256]

    const int* es = edges;
    const int* et = edges + EQ;
    float* out = (float*)d_out;

    int nb = (N + 255) / 256;

    // --- CSR build ---
    hipMemsetAsync(cnt, 0, (size_t)N * sizeof(int), stream);
    hist_kernel<<<(E + 255) / 256, 256, 0, stream>>>(adj_row, cnt, E);
    block_sum_kernel<<<nb, 256, 0, stream>>>(cnt, sums, N);
    scan_sums_kernel<<<1, 256, 0, stream>>>(sums, nb, row_ptr + N);
    scan_block_kernel<<<nb, 256, 0, stream>>>(cnt, sums, row_ptr, cursor, N);
    scatter_perm_kernel<<<(E + 255) / 256, 256, 0, stream>>>(adj_row, adj_col,
                                                             cursor, perm, E);

    // --- x slot ---
    int total_u2 = N * 64;
    compute_x_kernel<<<2048, 256, 0, stream>>>(node_vectors, node_weight, cmb,
                                               total_u2);

    // --- one_hop / two_hop via uint4 gather ---
    const uint4* cmb4 = (const uint4*)cmb;
    int gthreads = N * 64;
    int gblocks = (gthreads + 255) / 256;
    gather_hop_kernel<<<gblocks, 256, 0, stream>>>(
        row_ptr, perm, cmb4, (uint4*)cmb4 + SLOT_OH_U4, N);
    gather_hop_kernel<<<gblocks, 256, 0, stream>>>(
        row_ptr, perm, cmb4 + SLOT_OH_U4, (uint4*)cmb4 + SLOT_TH_U4, N);

    // --- queries ---
    int qthreads = EQ * 32;
    query_kernel<<<(qthreads + 255) / 256, 256, 0, stream>>>(
        es, et, cmb4, row_ptr, out, EQ);
}

// Round 6
// 270.569 us; speedup vs baseline: 5.4129x; 1.0014x over previous
//
#include <hip/hip_runtime.h>

#define DIM 256
// combined layout: per node 3 slots (x, oh, th), each 256 bf16 = 512 B
// node stride: 1536 B = 192 uint2 = 96 uint4
#define NODE_U2 192
#define NODE_U4 96
#define SLOT_OH_U2 64
#define SLOT_TH_U2 128
#define SLOT_OH_U4 32
#define SLOT_TH_U4 64

typedef unsigned int u32x4 __attribute__((ext_vector_type(4)));

// ---- bf16 helpers (manual, RNE pack / exact unpack) -----------------------
__device__ __forceinline__ unsigned int f2bf_rne(float f) {
    unsigned int u = __float_as_uint(f);
    return (u + 0x7fffu + ((u >> 16) & 1u)) >> 16;
}
__device__ __forceinline__ float bf_lo(unsigned int u) {
    return __uint_as_float(u << 16);
}
__device__ __forceinline__ float bf_hi(unsigned int u) {
    return __uint_as_float(u & 0xffff0000u);
}
__device__ __forceinline__ unsigned int pack2(float a, float b) {
    return f2bf_rne(a) | (f2bf_rne(b) << 16);
}

// ---- forced-MLP load primitives (compiler cannot serialize these) ---------
#define GLD_U4(dstv, p) \
    asm volatile("global_load_dwordx4 %0, %1, off" : "=v"(dstv) : "v"(p))
#define GLD_DW(dsts, p) \
    asm volatile("global_load_dword %0, %1, off" : "=v"(dsts) : "v"(p))
#define VMWAIT(n)                                                        \
    do {                                                                 \
        asm volatile("s_waitcnt vmcnt(%0)" ::"i"(n) : "memory");         \
        __builtin_amdgcn_sched_barrier(0);                               \
    } while (0)

#define ACC8V(v)                                          \
    do {                                                  \
        a0 += bf_lo((v)[0]); a1 += bf_hi((v)[0]);         \
        a2 += bf_lo((v)[1]); a3 += bf_hi((v)[1]);         \
        a4 += bf_lo((v)[2]); a5 += bf_hi((v)[2]);         \
        a6 += bf_lo((v)[3]); a7 += bf_hi((v)[3]);         \
    } while (0)

// ---------------------------------------------------------------------------
// 1) fused: combined[node][slot x] = bf16(nv * w)  AND  histogram of adj_row
// ---------------------------------------------------------------------------
__global__ void x_and_hist_kernel(const float* __restrict__ nv,
                                  const float* __restrict__ w,
                                  uint2* __restrict__ cmb,
                                  int total_u2,
                                  const int* __restrict__ adj_row,
                                  int* __restrict__ cnt, int E) {
    int i0 = blockIdx.x * blockDim.x + threadIdx.x;
    int stride = gridDim.x * blockDim.x;
    for (int i = i0; i < total_u2; i += stride) {
        float4 v = reinterpret_cast<const float4*>(nv)[i];
        int node = i >> 6;
        int j = i & 63;
        float wt = w[node];
        uint2 r;
        r.x = pack2(v.x * wt, v.y * wt);
        r.y = pack2(v.z * wt, v.w * wt);
        cmb[(size_t)node * NODE_U2 + j] = r;
    }
    for (int e = i0; e < E; e += stride) {
        atomicAdd(&cnt[adj_row[e]], 1);
    }
}

// ---------------------------------------------------------------------------
// CSR build (scan hierarchy)
// ---------------------------------------------------------------------------
__global__ void block_sum_kernel(const int* __restrict__ cnt,
                                 int* __restrict__ sums, int n) {
    __shared__ int lds[256];
    int i = blockIdx.x * 256 + threadIdx.x;
    lds[threadIdx.x] = (i < n) ? cnt[i] : 0;
    __syncthreads();
    #pragma unroll
    for (int off = 128; off > 0; off >>= 1) {
        if (threadIdx.x < off) lds[threadIdx.x] += lds[threadIdx.x + off];
        __syncthreads();
    }
    if (threadIdx.x == 0) sums[blockIdx.x] = lds[0];
}

__global__ void scan_sums_kernel(int* __restrict__ sums, int nb,
                                 int* __restrict__ row_ptr_n) {
    __shared__ int lds[256];
    int v = (threadIdx.x < nb) ? sums[threadIdx.x] : 0;
    lds[threadIdx.x] = v;
    __syncthreads();
    #pragma unroll
    for (int off = 1; off < 256; off <<= 1) {
        int t = (threadIdx.x >= off) ? lds[threadIdx.x - off] : 0;
        __syncthreads();
        lds[threadIdx.x] += t;
        __syncthreads();
    }
    if (threadIdx.x < nb) sums[threadIdx.x] = lds[threadIdx.x] - v;
    if (threadIdx.x == 255) *row_ptr_n = lds[255];
}

__global__ void scan_block_kernel(const int* __restrict__ cnt,
                                  const int* __restrict__ sums,
                                  int* __restrict__ row_ptr,
                                  int* __restrict__ cursor, int n) {
    __shared__ int lds[256];
    int i = blockIdx.x * 256 + threadIdx.x;
    int v = (i < n) ? cnt[i] : 0;
    lds[threadIdx.x] = v;
    __syncthreads();
    #pragma unroll
    for (int off = 1; off < 256; off <<= 1) {
        int t = (threadIdx.x >= off) ? lds[threadIdx.x - off] : 0;
        __syncthreads();
        lds[threadIdx.x] += t;
        __syncthreads();
    }
    if (i < n) {
        int excl = sums[blockIdx.x] + lds[threadIdx.x] - v;
        row_ptr[i] = excl;
        cursor[i] = excl;
    }
}

__global__ void scatter_perm_kernel(const int* __restrict__ row,
                                    const int* __restrict__ col,
                                    int* __restrict__ cursor,
                                    int* __restrict__ perm, int nedges) {
    int e = blockIdx.x * blockDim.x + threadIdx.x;
    if (e < nedges) {
        int pos = atomicAdd(&cursor[row[e]], 1);
        perm[pos] = col[e];
    }
}

// ---------------------------------------------------------------------------
// Gather segment-sum, one wave per row. Halves own CONTIGUOUS edge
// sub-ranges per batch; inline-asm loads with manual vmcnt force real MLP
// (8 row-loads in flight per half at peak).
// ---------------------------------------------------------------------------
__global__ void gather_hop_kernel(const int* __restrict__ row_ptr,
                                  const int* __restrict__ perm,
                                  const u32x4* __restrict__ src,
                                  u32x4* __restrict__ dst, int n) {
    int gid = blockIdx.x * blockDim.x + threadIdx.x;
    int r = gid >> 6;
    if (r >= n) return;
    int lane = gid & 63;
    int h = lane >> 5;      // half-wave id
    int l = lane & 31;      // uint4 index within 512B row

    int beg = row_ptr[r];
    int end = row_ptr[r + 1];
    int len = end - beg;
    int nb8 = len >> 4;          // batches of 16 edges (8 per half)
    int rem = len & 15;

    float a0 = 0.f, a1 = 0.f, a2 = 0.f, a3 = 0.f;
    float a4 = 0.f, a5 = 0.f, a6 = 0.f, a7 = 0.f;

    for (int b = 0; b < nb8; ++b) {
        const int* pp = perm + beg + (b << 4) + (h << 3);
        int c0, c1, c2, c3, c4, c5, c6, c7;
        GLD_DW(c0, pp + 0); GLD_DW(c1, pp + 1);
        GLD_DW(c2, pp + 2); GLD_DW(c3, pp + 3);
        GLD_DW(c4, pp + 4); GLD_DW(c5, pp + 5);
        GLD_DW(c6, pp + 6); GLD_DW(c7, pp + 7);
        VMWAIT(0);
        u32x4 v0, v1, v2, v3, v4, v5, v6, v7;
        GLD_U4(v0, src + (size_t)(unsigned)c0 * NODE_U4 + l);
        GLD_U4(v1, src + (size_t)(unsigned)c1 * NODE_U4 + l);
        GLD_U4(v2, src + (size_t)(unsigned)c2 * NODE_U4 + l);
        GLD_U4(v3, src + (size_t)(unsigned)c3 * NODE_U4 + l);
        GLD_U4(v4, src + (size_t)(unsigned)c4 * NODE_U4 + l);
        GLD_U4(v5, src + (size_t)(unsigned)c5 * NODE_U4 + l);
        GLD_U4(v6, src + (size_t)(unsigned)c6 * NODE_U4 + l);
        GLD_U4(v7, src + (size_t)(unsigned)c7 * NODE_U4 + l);
        VMWAIT(4);
        ACC8V(v0); ACC8V(v1); ACC8V(v2); ACC8V(v3);
        VMWAIT(0);
        ACC8V(v4); ACC8V(v5); ACC8V(v6); ACC8V(v7);
    }

    int tb = beg + (nb8 << 4);
    if (rem & 8) {              // 4 edges per half
        const int* pp = perm + tb + (h << 2);
        int c0, c1, c2, c3;
        GLD_DW(c0, pp + 0); GLD_DW(c1, pp + 1);
        GLD_DW(c2, pp + 2); GLD_DW(c3, pp + 3);
        VMWAIT(0);
        u32x4 v0, v1, v2, v3;
        GLD_U4(v0, src + (size_t)(unsigned)c0 * NODE_U4 + l);
        GLD_U4(v1, src + (size_t)(unsigned)c1 * NODE_U4 + l);
        GLD_U4(v2, src + (size_t)(unsigned)c2 * NODE_U4 + l);
        GLD_U4(v3, src + (size_t)(unsigned)c3 * NODE_U4 + l);
        VMWAIT(0);
        ACC8V(v0); ACC8V(v1); ACC8V(v2); ACC8V(v3);
        tb += 8;
    }
    if (rem & 4) {              // 2 edges per half
        const int* pp = perm + tb + (h << 1);
        int c0, c1;
        GLD_DW(c0, pp + 0); GLD_DW(c1, pp + 1);
        VMWAIT(0);
        u32x4 v0, v1;
        GLD_U4(v0, src + (size_t)(unsigned)c0 * NODE_U4 + l);
        GLD_U4(v1, src + (size_t)(unsigned)c1 * NODE_U4 + l);
        VMWAIT(0);
        ACC8V(v0); ACC8V(v1);
        tb += 4;
    }
    // scalar tail: 0..3 edges, halves interleave (plain loads, after drain)
    for (int e = tb + h; e < end; e += 2) {
        u32x4 v = src[(size_t)(unsigned)perm[e] * NODE_U4 + l];
        ACC8V(v);
    }

    // combine halves
    a0 += __shfl_xor(a0, 32); a1 += __shfl_xor(a1, 32);
    a2 += __shfl_xor(a2, 32); a3 += __shfl_xor(a3, 32);
    a4 += __shfl_xor(a4, 32); a5 += __shfl_xor(a5, 32);
    a6 += __shfl_xor(a6, 32); a7 += __shfl_xor(a7, 32);

    if (lane < 32) {
        u32x4 o;
        o[0] = pack2(a0, a1);
        o[1] = pack2(a2, a3);
        o[2] = pack2(a4, a5);
        o[3] = pack2(a6, a7);
        dst[(size_t)r * NODE_U4 + l] = o;
    }
}

// ---------------------------------------------------------------------------
// Query: 32 lanes per query (uint4 loads), 2 queries per wave.
// ---------------------------------------------------------------------------
__global__ void query_kernel(const int* __restrict__ es,
                             const int* __restrict__ et,
                             const uint4* __restrict__ cmb4,
                             const int* __restrict__ row_ptr,
                             float* __restrict__ out, int nq) {
    int gid = blockIdx.x * blockDim.x + threadIdx.x;
    int q = gid >> 5;
    if (q >= nq) return;
    int l = gid & 31;

    int s = es[q];
    int t = et[q];

    const uint4* ns = cmb4 + (size_t)s * NODE_U4;
    const uint4* nt = cmb4 + (size_t)t * NODE_U4;

    uint4 vxs = ns[l];
    uint4 vos = ns[SLOT_OH_U4 + l];
    uint4 vts = ns[SLOT_TH_U4 + l];
    uint4 vxt = nt[l];
    uint4 vot = nt[SLOT_OH_U4 + l];
    uint4 vtt = nt[SLOT_TH_U4 + l];
    float ds = (float)(row_ptr[s + 1] - row_ptr[s]);
    float dt = (float)(row_ptr[t + 1] - row_ptr[t]);

    float c11 = 0.f, c12 = 0.f, c22 = 0.f, cs = 0.f;
    const unsigned int* pxs = (const unsigned int*)&vxs;
    const unsigned int* pxt = (const unsigned int*)&vxt;
    const unsigned int* pos_ = (const unsigned int*)&vos;
    const unsigned int* pot = (const unsigned int*)&vot;
    const unsigned int* pts = (const unsigned int*)&vts;
    const unsigned int* ptt = (const unsigned int*)&vtt;
    #pragma unroll
    for (int k = 0; k < 4; ++k) {
        {
            float fxs = bf_lo(pxs[k]), fxt = bf_lo(pxt[k]);
            float fos = bf_lo(pos_[k]), fot = bf_lo(pot[k]);
            float fts = bf_lo(pts[k]), ftt = bf_lo(ptt[k]);
            c11 += fos * fot;
            c12 += fos * ftt + fts * fot;
            float as = fts - ds * fxs;
            float bt = ftt - dt * fxt;
            c22 += as * bt;
            cs  += fos * fts + fot * ftt;
        }
        {
            float fxs = bf_hi(pxs[k]), fxt = bf_hi(pxt[k]);
            float fos = bf_hi(pos_[k]), fot = bf_hi(pot[k]);
            float fts = bf_hi(pts[k]), ftt = bf_hi(ptt[k]);
            c11 += fos * fot;
            c12 += fos * ftt + fts * fot;
            float as = fts - ds * fxs;
            float bt = ftt - dt * fxt;
            c22 += as * bt;
            cs  += fos * fts + fot * ftt;
        }
    }

    #pragma unroll
    for (int off = 16; off > 0; off >>= 1) {
        c11 += __shfl_xor(c11, off);
        c12 += __shfl_xor(c12, off);
        c22 += __shfl_xor(c22, off);
        cs  += __shfl_xor(cs,  off);
    }

    if (l == 0) {
        out[q]          = c11;
        out[nq + q]     = c12;
        out[2 * nq + q] = c22;
        out[3 * nq + q] = cs;
    }
}

// ---------------------------------------------------------------------------
extern "C" void kernel_launch(void* const* d_in, const int* in_sizes, int n_in,
                              void* d_out, int out_size, void* d_ws, size_t ws_size,
                              hipStream_t stream) {
    const int*   edges        = (const int*)  d_in[0];  // [2, EQ]
    const int*   adj_row      = (const int*)  d_in[1];  // [E]
    const int*   adj_col      = (const int*)  d_in[2];  // [E]
    const float* node_weight  = (const float*)d_in[3];  // [N]
    const float* node_vectors = (const float*)d_in[4];  // [N, DIM]

    const int EQ = in_sizes[0] / 2;
    const int E  = in_sizes[1];
    const int N  = in_sizes[3];

    // workspace: combined bf16 [N][3][256] then CSR arrays
    uint2* cmb = (uint2*)d_ws;                          // N * 192 uint2 = 76.8 MB
    int* row_ptr = (int*)(cmb + (size_t)N * NODE_U2);   // [N+1]
    int* cursor  = row_ptr + (N + 1);                   // [N]
    int* cnt     = cursor + N;                          // [N]
    int* perm    = cnt + N;                             // [E]
    int* sums    = perm + E;                            // [<=256]

    const int* es = edges;
    const int* et = edges + EQ;
    float* out = (float*)d_out;

    int nb = (N + 255) / 256;

    // --- fused x + histogram ---
    hipMemsetAsync(cnt, 0, (size_t)N * sizeof(int), stream);
    int total_u2 = N * 64;
    x_and_hist_kernel<<<2048, 256, 0, stream>>>(node_vectors, node_weight, cmb,
                                                total_u2, adj_row, cnt, E);

    // --- CSR scan + permutation ---
    block_sum_kernel<<<nb, 256, 0, stream>>>(cnt, sums, N);
    scan_sums_kernel<<<1, 256, 0, stream>>>(sums, nb, row_ptr + N);
    scan_block_kernel<<<nb, 256, 0, stream>>>(cnt, sums, row_ptr, cursor, N);
    scatter_perm_kernel<<<(E + 255) / 256, 256, 0, stream>>>(adj_row, adj_col,
                                                             cursor, perm, E);

    // --- one_hop / two_hop via forced-MLP gather ---
    const u32x4* cmb4 = (const u32x4*)cmb;
    int gthreads = N * 64;
    int gblocks = (gthreads + 255) / 256;
    gather_hop_kernel<<<gblocks, 256, 0, stream>>>(
        row_ptr, perm, cmb4, (u32x4*)cmb4 + SLOT_OH_U4, N);
    gather_hop_kernel<<<gblocks, 256, 0, stream>>>(
        row_ptr, perm, cmb4 + SLOT_OH_U4, (u32x4*)cmb4 + SLOT_TH_U4, N);

    // --- queries ---
    int qthreads = EQ * 32;
    query_kernel<<<(qthreads + 255) / 256, 256, 0, stream>>>(
        es, et, (const uint4*)cmb4, row_ptr, out, EQ);
}